// Round 10
// baseline (651.007 us; speedup 1.0000x reference)
//
#include <hip/hip_runtime.h>
#include <hip/hip_bf16.h>

#define NN 8192
#define MM 16384
#define EE 131072
#define K2 32768

typedef unsigned short u16;
typedef unsigned int u32;
typedef __attribute__((ext_vector_type(8))) short bf16x8;
typedef __attribute__((ext_vector_type(4))) float f32x4;
typedef __attribute__((ext_vector_type(4))) float f4;

__device__ __forceinline__ u16 f2bf(float f){
  union { float f; unsigned u; } x; x.f = f;
  return (u16)((x.u + 0x7FFFu + ((x.u >> 16) & 1u)) >> 16);   // RNE
}

__device__ __forceinline__ bf16x8 cvt8(f4 a, f4 b){            // RNE path (prep kernels)
  bf16x8 r;
  r[0]=(short)f2bf(a.x); r[1]=(short)f2bf(a.y);
  r[2]=(short)f2bf(a.z); r[3]=(short)f2bf(a.w);
  r[4]=(short)f2bf(b.x); r[5]=(short)f2bf(b.y);
  r[6]=(short)f2bf(b.z); r[7]=(short)f2bf(b.w);
  return r;
}

// truncating pack: one v_perm_b32 per 2 floats (hot path: fuse_gemm A-convert)
__device__ __forceinline__ bf16x8 cvt8t(f4 a, f4 b){
  union { u32 u[4]; bf16x8 v; } r;
  r.u[0] = __builtin_amdgcn_perm(__float_as_uint(a.y), __float_as_uint(a.x), 0x07060302u);
  r.u[1] = __builtin_amdgcn_perm(__float_as_uint(a.w), __float_as_uint(a.z), 0x07060302u);
  r.u[2] = __builtin_amdgcn_perm(__float_as_uint(b.y), __float_as_uint(b.x), 0x07060302u);
  r.u[3] = __builtin_amdgcn_perm(__float_as_uint(b.w), __float_as_uint(b.z), 0x07060302u);
  return r.v;
}

// WfT[co][j] = bf16(W_fuse[(co>>7)*128 + j][co&127])
__global__ void wft_k(const float* __restrict__ W_fuse, u16* __restrict__ WfT){
  int co = blockIdx.x, j = threadIdx.x;
  int c = co >> 7, o = co & 127;
  WfT[co*128 + j] = f2bf(W_fuse[(c*128 + j)*128 + o]);
}

// BpT[o][2m+c] = bf16(sum_j feat_b[m][j] * W_fuse[c*128+j][o]); packed u32 (c0|c1<<16), uint4 stores
__global__ __launch_bounds__(128) void prep_bpt(const float* __restrict__ feat_b,
                                                const u16* __restrict__ WfT,
                                                u32* __restrict__ BpT32){
  int t = threadIdx.x, w = t >> 6, l = t & 63;
  int lr = l & 15, lk = l >> 4;
  int mrow = blockIdx.x*32 + w*16;               // 512 blocks x 2 waves
  f32x4 acc[16] = {};
  const float* ap = feat_b + (size_t)(mrow + lr)*128 + lk*8;
  #pragma unroll
  for (int ks = 0; ks < 4; ++ks){
    f4 a0 = *(const f4*)(ap + ks*32);
    f4 a1 = *(const f4*)(ap + ks*32 + 4);
    bf16x8 a = cvt8(a0, a1);
    #pragma unroll
    for (int cf = 0; cf < 16; ++cf){
      bf16x8 b = *(const bf16x8*)(WfT + (cf*16 + lr)*128 + ks*32 + lk*8);
      acc[cf] = __builtin_amdgcn_mfma_f32_16x16x32_bf16(a, b, acc[cf], 0, 0, 0);
    }
  }
  #pragma unroll
  for (int cf = 0; cf < 8; ++cf){
    int o = cf*16 + lr;
    uint4 v;
    v.x = (u32)f2bf(acc[cf][0]) | ((u32)f2bf(acc[cf+8][0]) << 16);
    v.y = (u32)f2bf(acc[cf][1]) | ((u32)f2bf(acc[cf+8][1]) << 16);
    v.z = (u32)f2bf(acc[cf][2]) | ((u32)f2bf(acc[cf+8][2]) << 16);
    v.w = (u32)f2bf(acc[cf][3]) | ((u32)f2bf(acc[cf+8][3]) << 16);
    *(uint4*)(BpT32 + (size_t)o*16384 + mrow + lk*4) = v;
  }
}

// CSR build
__global__ void hist_k(const int* __restrict__ dst, int* __restrict__ hist){
  int e = blockIdx.x*256 + threadIdx.x;
  atomicAdd(hist + dst[e], 1);
}

__global__ void scan_k(const int* __restrict__ hist, int* __restrict__ off,
                       int* __restrict__ cursor){
  __shared__ int part[256];
  int t = threadIdx.x;
  int loc[32]; int s = 0;
  #pragma unroll
  for (int i = 0; i < 32; ++i){ loc[i] = hist[t*32 + i]; s += loc[i]; }
  part[t] = s;
  __syncthreads();
  for (int d = 1; d < 256; d <<= 1){
    int v = (t >= d) ? part[t-d] : 0;
    __syncthreads();
    part[t] += v;
    __syncthreads();
  }
  int run = (t > 0) ? part[t-1] : 0;
  #pragma unroll
  for (int i = 0; i < 32; ++i){ off[t*32+i] = run; cursor[t*32+i] = run; run += loc[i]; }
  if (t == 255) off[NN] = run;
}

__global__ void fill_k(const int* __restrict__ src, const int* __restrict__ dst,
                       int* __restrict__ cursor, int* __restrict__ eidx){
  int e = blockIdx.x*256 + threadIdx.x;
  int pos = atomicAdd(cursor + dst[e], 1);
  eidx[pos] = src[e];
}

// agg: zout[n] = sum_{e: dst[e]=n} zin[src[e]]
__global__ __launch_bounds__(256) void agg_k(const float* __restrict__ zin,
                                             float* __restrict__ zout,
                                             const int* __restrict__ off,
                                             const int* __restrict__ eidx){
  int t = threadIdx.x;
  int node = blockIdx.x*8 + (t >> 5);
  int c = (t & 31)*4;
  int s = off[node], e = off[node+1];
  float a0=0.f, a1=0.f, a2=0.f, a3=0.f;
  for (int j = s; j < e; ++j){
    f4 v = *(const f4*)(zin + (size_t)eidx[j]*128 + c);
    a0 += v.x; a1 += v.y; a2 += v.z; a3 += v.w;
  }
  f4 r; r.x=a0; r.y=a1; r.z=a2; r.w=a3;
  *(f4*)(zout + (size_t)node*128 + c) = r;
}

// out = [feat_a, deg*feat_a, z0, z1, z2] @ Wcat + biases   (f32)
__global__ __launch_bounds__(256) void proj_all(
    const float* __restrict__ feat_a, const float* __restrict__ deg,
    const float* __restrict__ z0, const float* __restrict__ z1, const float* __restrict__ z2,
    const float* __restrict__ W_prev, const float* __restrict__ W_deg, const float* __restrict__ W_r,
    const float* __restrict__ b_prev, const float* __restrict__ b_deg,
    const float* __restrict__ b_r, const float* __restrict__ b_fuse,
    float* __restrict__ out)
{
  __shared__ float Xs[32][64];
  __shared__ float Ws[64][128];
  int t = threadIdx.x;
  int rbase = blockIdx.x*32;
  int o0 = (t & 15)*8, r0 = (t >> 4)*2;
  float acc[2][8] = {};
  for (int p = 0; p < 10; ++p){
    int seg = p >> 1, half = p & 1;
    {
      int row = t >> 3, e8 = t & 7;
      const float* bp = (seg <= 1) ? feat_a : (seg == 2) ? z0 : (seg == 3) ? z1 : z2;
      const float* sp = bp + (size_t)(rbase+row)*128 + half*64 + e8*8;
      f4 v0 = *(const f4*)sp;
      f4 v1 = *(const f4*)(sp+4);
      if (seg == 1){
        float d = deg[rbase+row];
        v0 *= d; v1 *= d;
      }
      *(f4*)&Xs[row][e8*8]   = v0;
      *(f4*)&Xs[row][e8*8+4] = v1;
    }
    #pragma unroll
    for (int it = 0; it < 8; ++it){
      int lin = it*1024 + t*4;
      int wr = lin >> 7, wc = lin & 127;
      int ksrc = p*64 + wr;
      int sg = ksrc >> 7, kin = ksrc & 127;
      const float* wp = (sg == 0) ? W_prev : (sg == 1) ? W_deg : (W_r + (size_t)(sg-2)*16384);
      *(f4*)&Ws[wr][wc] = *(const f4*)(wp + kin*128 + wc);
    }
    __syncthreads();
    #pragma unroll 8
    for (int kk = 0; kk < 64; ++kk){
      float x0 = Xs[r0][kk], x1 = Xs[r0+1][kk];
      f4 wa = *(const f4*)&Ws[kk][o0];
      f4 wb = *(const f4*)&Ws[kk][o0+4];
      acc[0][0]=fmaf(x0,wa.x,acc[0][0]); acc[0][1]=fmaf(x0,wa.y,acc[0][1]);
      acc[0][2]=fmaf(x0,wa.z,acc[0][2]); acc[0][3]=fmaf(x0,wa.w,acc[0][3]);
      acc[0][4]=fmaf(x0,wb.x,acc[0][4]); acc[0][5]=fmaf(x0,wb.y,acc[0][5]);
      acc[0][6]=fmaf(x0,wb.z,acc[0][6]); acc[0][7]=fmaf(x0,wb.w,acc[0][7]);
      acc[1][0]=fmaf(x1,wa.x,acc[1][0]); acc[1][1]=fmaf(x1,wa.y,acc[1][1]);
      acc[1][2]=fmaf(x1,wa.z,acc[1][2]); acc[1][3]=fmaf(x1,wa.w,acc[1][3]);
      acc[1][4]=fmaf(x1,wb.x,acc[1][4]); acc[1][5]=fmaf(x1,wb.y,acc[1][5]);
      acc[1][6]=fmaf(x1,wb.z,acc[1][6]); acc[1][7]=fmaf(x1,wb.w,acc[1][7]);
    }
    __syncthreads();
  }
  #pragma unroll
  for (int i = 0; i < 2; ++i){
    int r = rbase + r0 + i;
    #pragma unroll
    for (int j = 0; j < 8; ++j){
      int o = o0 + j;
      float bias = b_prev[o] + b_deg[o] + b_fuse[o] + b_r[o] + b_r[128+o] + b_r[256+o];
      out[(size_t)r*128 + o] = acc[i][j] + bias;
    }
  }
}

// C += pm_pd_flat(8192x32768 f32->bf16) @ Bp(32768x128 bf16)
// Verbatim R7 structure; ONLY change: __launch_bounds__ min-waves 2 -> 3
// (VGPR cap 256 -> 168) to probe the occupancy lever.
__global__ __launch_bounds__(256, 3) void fuse_gemm(const float* __restrict__ A,
                                                    const u16* __restrict__ BpT,
                                                    float* __restrict__ out){
  __shared__ u16 Bs[128*64];
  int b = blockIdx.x;
  int rowtile = b & 63, kc = b >> 6;
  int t = threadIdx.x, w = t >> 6, l = t & 63;
  int lr = l & 15, lk = l >> 4;
  size_t kbase = (size_t)kc*4096;
  int row0 = rowtile*128 + w*32 + lr;
  const float* a0p = A + (size_t)row0*K2 + kbase + lk*8;
  const float* a1p = a0p + (size_t)16*K2;
  f32x4 acc[2][8] = {};
  f4 Ar[2][8];
  // prologue: prefetch tile 0
  {
    const f4* p0 = (const f4*)a0p;
    const f4* p1 = (const f4*)a1p;
    Ar[0][0] = __builtin_nontemporal_load(p0);
    Ar[0][1] = __builtin_nontemporal_load(p0 + 1);
    Ar[0][2] = __builtin_nontemporal_load(p1);
    Ar[0][3] = __builtin_nontemporal_load(p1 + 1);
    Ar[0][4] = __builtin_nontemporal_load(p0 + 8);   // +32 floats
    Ar[0][5] = __builtin_nontemporal_load(p0 + 9);
    Ar[0][6] = __builtin_nontemporal_load(p1 + 8);
    Ar[0][7] = __builtin_nontemporal_load(p1 + 9);
  }
  #pragma unroll 2
  for (int tile = 0; tile < 64; ++tile){
    int cur = tile & 1;                          // static after unroll-2
    // issue next tile's A-loads first (long-latency HBM stream)
    if (tile < 63){
      const f4* p0 = (const f4*)(a0p + (tile+1)*64);
      const f4* p1 = (const f4*)(a1p + (tile+1)*64);
      Ar[cur^1][0] = __builtin_nontemporal_load(p0);
      Ar[cur^1][1] = __builtin_nontemporal_load(p0 + 1);
      Ar[cur^1][2] = __builtin_nontemporal_load(p1);
      Ar[cur^1][3] = __builtin_nontemporal_load(p1 + 1);
      Ar[cur^1][4] = __builtin_nontemporal_load(p0 + 8);
      Ar[cur^1][5] = __builtin_nontemporal_load(p0 + 9);
      Ar[cur^1][6] = __builtin_nontemporal_load(p1 + 8);
      Ar[cur^1][7] = __builtin_nontemporal_load(p1 + 9);
    }
    // stage B tile (128 o x 64 k), 16B-slot XOR swizzle
    size_t kt = kbase + tile*64;
    #pragma unroll
    for (int pp = 0; pp < 4; ++pp){
      int q = pp*256 + t;
      int o = q >> 3, oct = q & 7;
      uint4 v = *(const uint4*)(BpT + (size_t)o*K2 + kt + oct*8);
      *(uint4*)((char*)Bs + o*128 + ((oct ^ (o & 7)) << 4)) = v;
    }
    __syncthreads();                             // drains staging + prefetch together
    #pragma unroll
    for (int s = 0; s < 2; ++s){
      bf16x8 a0 = cvt8t(Ar[cur][s*4+0], Ar[cur][s*4+1]);
      bf16x8 a1 = cvt8t(Ar[cur][s*4+2], Ar[cur][s*4+3]);
      int khalf = s*4 + lk;
      #pragma unroll
      for (int cf = 0; cf < 8; ++cf){
        int o = cf*16 + lr;
        bf16x8 bfr = *(const bf16x8*)((char*)Bs + o*128 + ((khalf ^ (o & 7)) << 4));
        acc[0][cf] = __builtin_amdgcn_mfma_f32_16x16x32_bf16(a0, bfr, acc[0][cf], 0, 0, 0);
        acc[1][cf] = __builtin_amdgcn_mfma_f32_16x16x32_bf16(a1, bfr, acc[1][cf], 0, 0, 0);
      }
    }
    __syncthreads();
  }
  int orow = rowtile*128 + w*32 + lk*4;
  #pragma unroll
  for (int rf = 0; rf < 2; ++rf){
    #pragma unroll
    for (int cf = 0; cf < 8; ++cf){
      #pragma unroll
      for (int j = 0; j < 4; ++j){
        unsafeAtomicAdd(out + (size_t)(orow + rf*16 + j)*128 + cf*16 + lr, acc[rf][cf][j]);
      }
    }
  }
}

// BatchNorm stats with half-ReLU on read; row-contiguous reads
__global__ __launch_bounds__(256) void colstats(const float* __restrict__ acc,
                                                float* __restrict__ gsum,
                                                float* __restrict__ gsumsq){
  __shared__ float s1[8][128], s2[8][128];
  int t = threadIdx.x;
  int c4 = (t & 31)*4, rsub = t >> 5;
  int rbase = blockIdx.x*32;
  f4 sum = {0,0,0,0}, sq = {0,0,0,0};
  #pragma unroll
  for (int i = 0; i < 4; ++i){
    f4 v = *(const f4*)(acc + (size_t)(rbase + rsub + i*8)*128 + c4);
    if (c4 >= 64){
      v.x=fmaxf(v.x,0.f); v.y=fmaxf(v.y,0.f); v.z=fmaxf(v.z,0.f); v.w=fmaxf(v.w,0.f);
    }
    sum += v; sq += v*v;
  }
  *(f4*)&s1[rsub][c4] = sum;
  *(f4*)&s2[rsub][c4] = sq;
  __syncthreads();
  if (t < 128){
    float a = 0.f, b2 = 0.f;
    #pragma unroll
    for (int r = 0; r < 8; ++r){ a += s1[r][t]; b2 += s2[r][t]; }
    unsafeAtomicAdd(gsum + t, a);
    unsafeAtomicAdd(gsumsq + t, b2);
  }
}

__global__ void bn_final(const float* __restrict__ gsum, const float* __restrict__ gsumsq,
                         const float* __restrict__ gamma, const float* __restrict__ beta,
                         float* __restrict__ scale, float* __restrict__ shift){
  int c = threadIdx.x;
  float mean = gsum[c] * (1.f/8192.f);
  float var  = gsumsq[c] * (1.f/8192.f) - mean*mean;
  float rstd = rsqrtf(var + 1e-5f);
  float sc = rstd * gamma[c];
  scale[c] = sc;
  shift[c] = beta[c] - mean*sc;
}

__global__ __launch_bounds__(256) void bn_apply(float* __restrict__ out,
                                                const float* __restrict__ scale,
                                                const float* __restrict__ shift){
  int i = blockIdx.x*256 + threadIdx.x;
  int j = i & 31;
  f4* o4 = (f4*)out;
  f4 v = o4[i];
  if (j >= 16){
    v.x=fmaxf(v.x,0.f); v.y=fmaxf(v.y,0.f); v.z=fmaxf(v.z,0.f); v.w=fmaxf(v.w,0.f);
  }
  f4 sc = *(const f4*)(scale + j*4);
  f4 sh = *(const f4*)(shift + j*4);
  v.x = fmaf(v.x,sc.x,sh.x); v.y = fmaf(v.y,sc.y,sh.y);
  v.z = fmaf(v.z,sc.z,sh.z); v.w = fmaf(v.w,sc.w,sh.w);
  o4[i] = v;
}

extern "C" void kernel_launch(void* const* d_in, const int* in_sizes, int n_in,
                              void* d_out, int out_size, void* d_ws, size_t ws_size,
                              hipStream_t stream) {
  const float* feat_a = (const float*)d_in[0];
  const float* feat_b = (const float*)d_in[1];
  const float* deg    = (const float*)d_in[2];
  const float* pm_pd  = (const float*)d_in[3];
  const int*   src    = (const int*)d_in[4];
  const int*   dst    = (const int*)d_in[5];
  const float* W_prev = (const float*)d_in[6];
  const float* b_prev = (const float*)d_in[7];
  const float* W_deg  = (const float*)d_in[8];
  const float* b_deg  = (const float*)d_in[9];
  const float* W_r    = (const float*)d_in[10];
  const float* b_r    = (const float*)d_in[11];
  const float* W_fuse = (const float*)d_in[12];
  const float* b_fuse = (const float*)d_in[13];
  const float* gamma  = (const float*)d_in[14];
  const float* beta   = (const float*)d_in[15];
  float* out = (float*)d_out;

  char* w = (char*)d_ws;
  u16*   BpT    = (u16*)  (w + 0);          // 8 MB interleaved B'
  float* z0     = (float*)(w + 8388608);
  float* z1     = (float*)(w + 12582912);
  float* ztmp   = (float*)(w + 16777216);
  float* z2     = (float*)(w + 20971520);
  u16*   WfT    = (u16*)  (w + 25165824);
  int*   hist   = (int*)  (w + 25231360);
  int*   off    = (int*)  (w + 25264128);
  int*   cursor = (int*)  (w + 25296912);
  int*   eidx   = (int*)  (w + 25329680);
  float* gsum   = (float*)(w + 25853968);
  float* gsumsq = gsum + 128;
  float* scale  = (float*)(w + 25854992);
  float* shift  = (float*)(w + 25855504);
  if (ws_size < (size_t)25856016) return;

  hipMemsetAsync(hist, 0, NN*sizeof(int), stream);
  hipMemsetAsync(gsum, 0, 256*sizeof(float), stream);

  wft_k<<<256, 128, 0, stream>>>(W_fuse, WfT);
  prep_bpt<<<MM/32, 128, 0, stream>>>(feat_b, WfT, (u32*)BpT);

  hist_k<<<EE/256, 256, 0, stream>>>(dst, hist);
  scan_k<<<1, 256, 0, stream>>>(hist, off, cursor);
  fill_k<<<EE/256, 256, 0, stream>>>(src, dst, cursor, eidx);

  agg_k<<<NN/8, 256, 0, stream>>>(feat_a, z0, off, eidx);
  agg_k<<<NN/8, 256, 0, stream>>>(z0, z1, off, eidx);
  agg_k<<<NN/8, 256, 0, stream>>>(z1, ztmp, off, eidx);
  agg_k<<<NN/8, 256, 0, stream>>>(ztmp, z2, off, eidx);

  proj_all<<<NN/32, 256, 0, stream>>>(feat_a, deg, z0, z1, z2,
                                      W_prev, W_deg, W_r, b_prev, b_deg, b_r, b_fuse, out);

  fuse_gemm<<<512, 256, 0, stream>>>(pm_pd, BpT, out);

  colstats<<<NN/32, 256, 0, stream>>>(out, gsum, gsumsq);
  bn_final<<<1, 128, 0, stream>>>(gsum, gsumsq, gamma, beta, scale, shift);
  bn_apply<<<NN*128/4/256, 256, 0, stream>>>(out, scale, shift);
}

// Round 11
// 448.247 us; speedup vs baseline: 1.4523x; 1.4523x over previous
//
#include <hip/hip_runtime.h>
#include <hip/hip_bf16.h>

#define NN 8192
#define MM 16384
#define EE 131072
#define K2 32768

typedef unsigned short u16;
typedef unsigned int u32;
typedef __attribute__((ext_vector_type(8))) short bf16x8;
typedef __attribute__((ext_vector_type(4))) float f32x4;
typedef __attribute__((ext_vector_type(4))) float f4;
typedef __attribute__((address_space(1))) const u32 gAS1u32;
typedef __attribute__((address_space(3))) u32 lAS3u32;

__device__ __forceinline__ u16 f2bf(float f){
  union { float f; unsigned u; } x; x.f = f;
  return (u16)((x.u + 0x7FFFu + ((x.u >> 16) & 1u)) >> 16);   // RNE
}

__device__ __forceinline__ bf16x8 cvt8(f4 a, f4 b){            // RNE path (prep kernels)
  bf16x8 r;
  r[0]=(short)f2bf(a.x); r[1]=(short)f2bf(a.y);
  r[2]=(short)f2bf(a.z); r[3]=(short)f2bf(a.w);
  r[4]=(short)f2bf(b.x); r[5]=(short)f2bf(b.y);
  r[6]=(short)f2bf(b.z); r[7]=(short)f2bf(b.w);
  return r;
}

// truncating pack: one v_perm_b32 per 2 floats (hot path: fuse_gemm A-convert)
__device__ __forceinline__ bf16x8 cvt8t(f4 a, f4 b){
  union { u32 u[4]; bf16x8 v; } r;
  r.u[0] = __builtin_amdgcn_perm(__float_as_uint(a.y), __float_as_uint(a.x), 0x07060302u);
  r.u[1] = __builtin_amdgcn_perm(__float_as_uint(a.w), __float_as_uint(a.z), 0x07060302u);
  r.u[2] = __builtin_amdgcn_perm(__float_as_uint(b.y), __float_as_uint(b.x), 0x07060302u);
  r.u[3] = __builtin_amdgcn_perm(__float_as_uint(b.w), __float_as_uint(b.z), 0x07060302u);
  return r.v;
}

// WfT[co][j] = bf16(W_fuse[(co>>7)*128 + j][co&127])
__global__ void wft_k(const float* __restrict__ W_fuse, u16* __restrict__ WfT){
  int co = blockIdx.x, j = threadIdx.x;
  int c = co >> 7, o = co & 127;
  WfT[co*128 + j] = f2bf(W_fuse[(c*128 + j)*128 + o]);
}

// BpT[o][2m+c] = bf16(sum_j feat_b[m][j] * W_fuse[c*128+j][o]); packed u32 (c0|c1<<16), uint4 stores
__global__ __launch_bounds__(128) void prep_bpt(const float* __restrict__ feat_b,
                                                const u16* __restrict__ WfT,
                                                u32* __restrict__ BpT32){
  int t = threadIdx.x, w = t >> 6, l = t & 63;
  int lr = l & 15, lk = l >> 4;
  int mrow = blockIdx.x*32 + w*16;               // 512 blocks x 2 waves
  f32x4 acc[16] = {};
  const float* ap = feat_b + (size_t)(mrow + lr)*128 + lk*8;
  #pragma unroll
  for (int ks = 0; ks < 4; ++ks){
    f4 a0 = *(const f4*)(ap + ks*32);
    f4 a1 = *(const f4*)(ap + ks*32 + 4);
    bf16x8 a = cvt8(a0, a1);
    #pragma unroll
    for (int cf = 0; cf < 16; ++cf){
      bf16x8 b = *(const bf16x8*)(WfT + (cf*16 + lr)*128 + ks*32 + lk*8);
      acc[cf] = __builtin_amdgcn_mfma_f32_16x16x32_bf16(a, b, acc[cf], 0, 0, 0);
    }
  }
  #pragma unroll
  for (int cf = 0; cf < 8; ++cf){
    int o = cf*16 + lr;
    uint4 v;
    v.x = (u32)f2bf(acc[cf][0]) | ((u32)f2bf(acc[cf+8][0]) << 16);
    v.y = (u32)f2bf(acc[cf][1]) | ((u32)f2bf(acc[cf+8][1]) << 16);
    v.z = (u32)f2bf(acc[cf][2]) | ((u32)f2bf(acc[cf+8][2]) << 16);
    v.w = (u32)f2bf(acc[cf][3]) | ((u32)f2bf(acc[cf+8][3]) << 16);
    *(uint4*)(BpT32 + (size_t)o*16384 + mrow + lk*4) = v;
  }
}

// CSR build
__global__ void hist_k(const int* __restrict__ dst, int* __restrict__ hist){
  int e = blockIdx.x*256 + threadIdx.x;
  atomicAdd(hist + dst[e], 1);
}

__global__ void scan_k(const int* __restrict__ hist, int* __restrict__ off,
                       int* __restrict__ cursor){
  __shared__ int part[256];
  int t = threadIdx.x;
  int loc[32]; int s = 0;
  #pragma unroll
  for (int i = 0; i < 32; ++i){ loc[i] = hist[t*32 + i]; s += loc[i]; }
  part[t] = s;
  __syncthreads();
  for (int d = 1; d < 256; d <<= 1){
    int v = (t >= d) ? part[t-d] : 0;
    __syncthreads();
    part[t] += v;
    __syncthreads();
  }
  int run = (t > 0) ? part[t-1] : 0;
  #pragma unroll
  for (int i = 0; i < 32; ++i){ off[t*32+i] = run; cursor[t*32+i] = run; run += loc[i]; }
  if (t == 255) off[NN] = run;
}

__global__ void fill_k(const int* __restrict__ src, const int* __restrict__ dst,
                       int* __restrict__ cursor, int* __restrict__ eidx){
  int e = blockIdx.x*256 + threadIdx.x;
  int pos = atomicAdd(cursor + dst[e], 1);
  eidx[pos] = src[e];
}

// agg: zout[n] = sum_{e: dst[e]=n} zin[src[e]]
__global__ __launch_bounds__(256) void agg_k(const float* __restrict__ zin,
                                             float* __restrict__ zout,
                                             const int* __restrict__ off,
                                             const int* __restrict__ eidx){
  int t = threadIdx.x;
  int node = blockIdx.x*8 + (t >> 5);
  int c = (t & 31)*4;
  int s = off[node], e = off[node+1];
  float a0=0.f, a1=0.f, a2=0.f, a3=0.f;
  for (int j = s; j < e; ++j){
    f4 v = *(const f4*)(zin + (size_t)eidx[j]*128 + c);
    a0 += v.x; a1 += v.y; a2 += v.z; a3 += v.w;
  }
  f4 r; r.x=a0; r.y=a1; r.z=a2; r.w=a3;
  *(f4*)(zout + (size_t)node*128 + c) = r;
}

// out = [feat_a, deg*feat_a, z0, z1, z2] @ Wcat + biases   (f32)
__global__ __launch_bounds__(256) void proj_all(
    const float* __restrict__ feat_a, const float* __restrict__ deg,
    const float* __restrict__ z0, const float* __restrict__ z1, const float* __restrict__ z2,
    const float* __restrict__ W_prev, const float* __restrict__ W_deg, const float* __restrict__ W_r,
    const float* __restrict__ b_prev, const float* __restrict__ b_deg,
    const float* __restrict__ b_r, const float* __restrict__ b_fuse,
    float* __restrict__ out)
{
  __shared__ float Xs[32][64];
  __shared__ float Ws[64][128];
  int t = threadIdx.x;
  int rbase = blockIdx.x*32;
  int o0 = (t & 15)*8, r0 = (t >> 4)*2;
  float acc[2][8] = {};
  for (int p = 0; p < 10; ++p){
    int seg = p >> 1, half = p & 1;
    {
      int row = t >> 3, e8 = t & 7;
      const float* bp = (seg <= 1) ? feat_a : (seg == 2) ? z0 : (seg == 3) ? z1 : z2;
      const float* sp = bp + (size_t)(rbase+row)*128 + half*64 + e8*8;
      f4 v0 = *(const f4*)sp;
      f4 v1 = *(const f4*)(sp+4);
      if (seg == 1){
        float d = deg[rbase+row];
        v0 *= d; v1 *= d;
      }
      *(f4*)&Xs[row][e8*8]   = v0;
      *(f4*)&Xs[row][e8*8+4] = v1;
    }
    #pragma unroll
    for (int it = 0; it < 8; ++it){
      int lin = it*1024 + t*4;
      int wr = lin >> 7, wc = lin & 127;
      int ksrc = p*64 + wr;
      int sg = ksrc >> 7, kin = ksrc & 127;
      const float* wp = (sg == 0) ? W_prev : (sg == 1) ? W_deg : (W_r + (size_t)(sg-2)*16384);
      *(f4*)&Ws[wr][wc] = *(const f4*)(wp + kin*128 + wc);
    }
    __syncthreads();
    #pragma unroll 8
    for (int kk = 0; kk < 64; ++kk){
      float x0 = Xs[r0][kk], x1 = Xs[r0+1][kk];
      f4 wa = *(const f4*)&Ws[kk][o0];
      f4 wb = *(const f4*)&Ws[kk][o0+4];
      acc[0][0]=fmaf(x0,wa.x,acc[0][0]); acc[0][1]=fmaf(x0,wa.y,acc[0][1]);
      acc[0][2]=fmaf(x0,wa.z,acc[0][2]); acc[0][3]=fmaf(x0,wa.w,acc[0][3]);
      acc[0][4]=fmaf(x0,wb.x,acc[0][4]); acc[0][5]=fmaf(x0,wb.y,acc[0][5]);
      acc[0][6]=fmaf(x0,wb.z,acc[0][6]); acc[0][7]=fmaf(x0,wb.w,acc[0][7]);
      acc[1][0]=fmaf(x1,wa.x,acc[1][0]); acc[1][1]=fmaf(x1,wa.y,acc[1][1]);
      acc[1][2]=fmaf(x1,wa.z,acc[1][2]); acc[1][3]=fmaf(x1,wa.w,acc[1][3]);
      acc[1][4]=fmaf(x1,wb.x,acc[1][4]); acc[1][5]=fmaf(x1,wb.y,acc[1][5]);
      acc[1][6]=fmaf(x1,wb.z,acc[1][6]); acc[1][7]=fmaf(x1,wb.w,acc[1][7]);
    }
    __syncthreads();
  }
  #pragma unroll
  for (int i = 0; i < 2; ++i){
    int r = rbase + r0 + i;
    #pragma unroll
    for (int j = 0; j < 8; ++j){
      int o = o0 + j;
      float bias = b_prev[o] + b_deg[o] + b_fuse[o] + b_r[o] + b_r[128+o] + b_r[256+o];
      out[(size_t)r*128 + o] = acc[i][j] + bias;
    }
  }
}

// C += pm_pd_flat(8192x32768 f32->bf16) @ Bp(32768x128 bf16)
// R7 structure; B-staging now via async global_load_lds (width=16):
// linear LDS dest (q*16), XOR swizzle moved to the GLOBAL source chunk index
// (rule: linear dest + inverse-swizzled source + swizzled read = identity).
__global__ __launch_bounds__(256, 2) void fuse_gemm(const float* __restrict__ A,
                                                    const u16* __restrict__ BpT,
                                                    float* __restrict__ out){
  __shared__ u16 Bs[128*64];
  int b = blockIdx.x;
  int rowtile = b & 63, kc = b >> 6;
  int t = threadIdx.x, w = t >> 6, l = t & 63;
  int lr = l & 15, lk = l >> 4;
  size_t kbase = (size_t)kc*4096;
  int row0 = rowtile*128 + w*32 + lr;
  const float* a0p = A + (size_t)row0*K2 + kbase + lk*8;
  const float* a1p = a0p + (size_t)16*K2;
  // per-thread staging constants: q = pp*256+t -> o = q>>3, oct = q&7
  f32x4 acc[2][8] = {};
  f4 Ar[2][8];
  // prologue: prefetch tile 0
  {
    const f4* p0 = (const f4*)a0p;
    const f4* p1 = (const f4*)a1p;
    Ar[0][0] = __builtin_nontemporal_load(p0);
    Ar[0][1] = __builtin_nontemporal_load(p0 + 1);
    Ar[0][2] = __builtin_nontemporal_load(p1);
    Ar[0][3] = __builtin_nontemporal_load(p1 + 1);
    Ar[0][4] = __builtin_nontemporal_load(p0 + 8);   // +32 floats
    Ar[0][5] = __builtin_nontemporal_load(p0 + 9);
    Ar[0][6] = __builtin_nontemporal_load(p1 + 8);
    Ar[0][7] = __builtin_nontemporal_load(p1 + 9);
  }
  #pragma unroll 2
  for (int tile = 0; tile < 64; ++tile){
    int cur = tile & 1;                          // static after unroll-2
    // issue next tile's A-loads first (long-latency HBM stream)
    if (tile < 63){
      const f4* p0 = (const f4*)(a0p + (tile+1)*64);
      const f4* p1 = (const f4*)(a1p + (tile+1)*64);
      Ar[cur^1][0] = __builtin_nontemporal_load(p0);
      Ar[cur^1][1] = __builtin_nontemporal_load(p0 + 1);
      Ar[cur^1][2] = __builtin_nontemporal_load(p1);
      Ar[cur^1][3] = __builtin_nontemporal_load(p1 + 1);
      Ar[cur^1][4] = __builtin_nontemporal_load(p0 + 8);
      Ar[cur^1][5] = __builtin_nontemporal_load(p0 + 9);
      Ar[cur^1][6] = __builtin_nontemporal_load(p1 + 8);
      Ar[cur^1][7] = __builtin_nontemporal_load(p1 + 9);
    }
    // stage B tile (128 o x 64 k) via async DMA: lane-linear LDS, swizzled source
    size_t kt = kbase + tile*64;
    #pragma unroll
    for (int pp = 0; pp < 4; ++pp){
      int q = pp*256 + t;
      int o = q >> 3, oct = q & 7;
      int soct = oct ^ (o & 7);                  // pre-swizzled source chunk
      __builtin_amdgcn_global_load_lds(
          (gAS1u32*)(BpT + (size_t)o*K2 + kt + soct*8),
          (lAS3u32*)((char*)Bs + q*16),
          16, 0, 0);
    }
    __syncthreads();                             // drains A-prefetch + B-DMA together
    #pragma unroll
    for (int s = 0; s < 2; ++s){
      bf16x8 a0 = cvt8t(Ar[cur][s*4+0], Ar[cur][s*4+1]);
      bf16x8 a1 = cvt8t(Ar[cur][s*4+2], Ar[cur][s*4+3]);
      int khalf = s*4 + lk;
      #pragma unroll
      for (int cf = 0; cf < 8; ++cf){
        int o = cf*16 + lr;
        bf16x8 bfr = *(const bf16x8*)((char*)Bs + o*128 + ((khalf ^ (o & 7)) << 4));
        acc[0][cf] = __builtin_amdgcn_mfma_f32_16x16x32_bf16(a0, bfr, acc[0][cf], 0, 0, 0);
        acc[1][cf] = __builtin_amdgcn_mfma_f32_16x16x32_bf16(a1, bfr, acc[1][cf], 0, 0, 0);
      }
    }
    __syncthreads();
  }
  int orow = rowtile*128 + w*32 + lk*4;
  #pragma unroll
  for (int rf = 0; rf < 2; ++rf){
    #pragma unroll
    for (int cf = 0; cf < 8; ++cf){
      #pragma unroll
      for (int j = 0; j < 4; ++j){
        unsafeAtomicAdd(out + (size_t)(orow + rf*16 + j)*128 + cf*16 + lr, acc[rf][cf][j]);
      }
    }
  }
}

// BatchNorm stats with half-ReLU on read; row-contiguous reads
__global__ __launch_bounds__(256) void colstats(const float* __restrict__ acc,
                                                float* __restrict__ gsum,
                                                float* __restrict__ gsumsq){
  __shared__ float s1[8][128], s2[8][128];
  int t = threadIdx.x;
  int c4 = (t & 31)*4, rsub = t >> 5;
  int rbase = blockIdx.x*32;
  f4 sum = {0,0,0,0}, sq = {0,0,0,0};
  #pragma unroll
  for (int i = 0; i < 4; ++i){
    f4 v = *(const f4*)(acc + (size_t)(rbase + rsub + i*8)*128 + c4);
    if (c4 >= 64){
      v.x=fmaxf(v.x,0.f); v.y=fmaxf(v.y,0.f); v.z=fmaxf(v.z,0.f); v.w=fmaxf(v.w,0.f);
    }
    sum += v; sq += v*v;
  }
  *(f4*)&s1[rsub][c4] = sum;
  *(f4*)&s2[rsub][c4] = sq;
  __syncthreads();
  if (t < 128){
    float a = 0.f, b2 = 0.f;
    #pragma unroll
    for (int r = 0; r < 8; ++r){ a += s1[r][t]; b2 += s2[r][t]; }
    unsafeAtomicAdd(gsum + t, a);
    unsafeAtomicAdd(gsumsq + t, b2);
  }
}

// merged bn_final + bn_apply: each block computes its 4 cols' scale/shift from gsum
__global__ __launch_bounds__(256) void bn_apply(float* __restrict__ out,
                                                const float* __restrict__ gsum,
                                                const float* __restrict__ gsumsq,
                                                const float* __restrict__ gamma,
                                                const float* __restrict__ beta){
  int i = blockIdx.x*256 + threadIdx.x;
  int j = i & 31;
  f4 sc, sh;
  #pragma unroll
  for (int k = 0; k < 4; ++k){
    int c = j*4 + k;
    float mean = gsum[c] * (1.f/8192.f);
    float var  = gsumsq[c] * (1.f/8192.f) - mean*mean;
    float s = rsqrtf(var + 1e-5f) * gamma[c];
    ((float*)&sc)[k] = s;
    ((float*)&sh)[k] = beta[c] - mean*s;
  }
  f4* o4 = (f4*)out;
  f4 v = o4[i];
  if (j >= 16){
    v.x=fmaxf(v.x,0.f); v.y=fmaxf(v.y,0.f); v.z=fmaxf(v.z,0.f); v.w=fmaxf(v.w,0.f);
  }
  v.x = fmaf(v.x,sc.x,sh.x); v.y = fmaf(v.y,sc.y,sh.y);
  v.z = fmaf(v.z,sc.z,sh.z); v.w = fmaf(v.w,sc.w,sh.w);
  o4[i] = v;
}

extern "C" void kernel_launch(void* const* d_in, const int* in_sizes, int n_in,
                              void* d_out, int out_size, void* d_ws, size_t ws_size,
                              hipStream_t stream) {
  const float* feat_a = (const float*)d_in[0];
  const float* feat_b = (const float*)d_in[1];
  const float* deg    = (const float*)d_in[2];
  const float* pm_pd  = (const float*)d_in[3];
  const int*   src    = (const int*)d_in[4];
  const int*   dst    = (const int*)d_in[5];
  const float* W_prev = (const float*)d_in[6];
  const float* b_prev = (const float*)d_in[7];
  const float* W_deg  = (const float*)d_in[8];
  const float* b_deg  = (const float*)d_in[9];
  const float* W_r    = (const float*)d_in[10];
  const float* b_r    = (const float*)d_in[11];
  const float* W_fuse = (const float*)d_in[12];
  const float* b_fuse = (const float*)d_in[13];
  const float* gamma  = (const float*)d_in[14];
  const float* beta   = (const float*)d_in[15];
  float* out = (float*)d_out;

  char* w = (char*)d_ws;
  u16*   BpT    = (u16*)  (w + 0);          // 8 MB interleaved B'
  float* z0     = (float*)(w + 8388608);
  float* z1     = (float*)(w + 12582912);
  float* ztmp   = (float*)(w + 16777216);
  float* z2     = (float*)(w + 20971520);
  u16*   WfT    = (u16*)  (w + 25165824);
  int*   hist   = (int*)  (w + 25231360);
  int*   off    = (int*)  (w + 25264128);
  int*   cursor = (int*)  (w + 25296912);
  int*   eidx   = (int*)  (w + 25329680);
  float* gsum   = (float*)(w + 25853968);
  float* gsumsq = gsum + 128;
  float* scale  = (float*)(w + 25854992);
  float* shift  = (float*)(w + 25855504);
  if (ws_size < (size_t)25856016) return;
  (void)scale; (void)shift;

  hipMemsetAsync(hist, 0, NN*sizeof(int), stream);
  hipMemsetAsync(gsum, 0, 256*sizeof(float), stream);

  wft_k<<<256, 128, 0, stream>>>(W_fuse, WfT);
  prep_bpt<<<MM/32, 128, 0, stream>>>(feat_b, WfT, (u32*)BpT);

  hist_k<<<EE/256, 256, 0, stream>>>(dst, hist);
  scan_k<<<1, 256, 0, stream>>>(hist, off, cursor);
  fill_k<<<EE/256, 256, 0, stream>>>(src, dst, cursor, eidx);

  agg_k<<<NN/8, 256, 0, stream>>>(feat_a, z0, off, eidx);
  agg_k<<<NN/8, 256, 0, stream>>>(z0, z1, off, eidx);
  agg_k<<<NN/8, 256, 0, stream>>>(z1, ztmp, off, eidx);
  agg_k<<<NN/8, 256, 0, stream>>>(ztmp, z2, off, eidx);

  proj_all<<<NN/32, 256, 0, stream>>>(feat_a, deg, z0, z1, z2,
                                      W_prev, W_deg, W_r, b_prev, b_deg, b_r, b_fuse, out);

  fuse_gemm<<<512, 256, 0, stream>>>(pm_pd, BpT, out);

  colstats<<<NN/32, 256, 0, stream>>>(out, gsum, gsumsq);
  bn_apply<<<NN*128/4/256, 256, 0, stream>>>(out, gsum, gsumsq, gamma, beta);
}

// Round 12
// 437.690 us; speedup vs baseline: 1.4874x; 1.0241x over previous
//
#include <hip/hip_runtime.h>
#include <hip/hip_bf16.h>

#define NN 8192
#define MM 16384
#define EE 131072
#define K2 32768

typedef unsigned short u16;
typedef unsigned int u32;
typedef __attribute__((ext_vector_type(8))) short bf16x8;
typedef __attribute__((ext_vector_type(4))) float f32x4;
typedef __attribute__((ext_vector_type(4))) float f4;

__device__ __forceinline__ u16 f2bf(float f){
  union { float f; unsigned u; } x; x.f = f;
  return (u16)((x.u + 0x7FFFu + ((x.u >> 16) & 1u)) >> 16);   // RNE
}

__device__ __forceinline__ bf16x8 cvt8(f4 a, f4 b){            // RNE path (prep kernels)
  bf16x8 r;
  r[0]=(short)f2bf(a.x); r[1]=(short)f2bf(a.y);
  r[2]=(short)f2bf(a.z); r[3]=(short)f2bf(a.w);
  r[4]=(short)f2bf(b.x); r[5]=(short)f2bf(b.y);
  r[6]=(short)f2bf(b.z); r[7]=(short)f2bf(b.w);
  return r;
}

// truncating pack: one v_perm_b32 per 2 floats (hot path: fuse_gemm A-convert)
__device__ __forceinline__ bf16x8 cvt8t(f4 a, f4 b){
  union { u32 u[4]; bf16x8 v; } r;
  r.u[0] = __builtin_amdgcn_perm(__float_as_uint(a.y), __float_as_uint(a.x), 0x07060302u);
  r.u[1] = __builtin_amdgcn_perm(__float_as_uint(a.w), __float_as_uint(a.z), 0x07060302u);
  r.u[2] = __builtin_amdgcn_perm(__float_as_uint(b.y), __float_as_uint(b.x), 0x07060302u);
  r.u[3] = __builtin_amdgcn_perm(__float_as_uint(b.w), __float_as_uint(b.z), 0x07060302u);
  return r.v;
}

// WfT[co][j] = bf16(W_fuse[(co>>7)*128 + j][co&127])
__global__ void wft_k(const float* __restrict__ W_fuse, u16* __restrict__ WfT){
  int co = blockIdx.x, j = threadIdx.x;
  int c = co >> 7, o = co & 127;
  WfT[co*128 + j] = f2bf(W_fuse[(c*128 + j)*128 + o]);
}

// BpT[o][2m+c] = bf16(sum_j feat_b[m][j] * W_fuse[c*128+j][o]); packed u32 (c0|c1<<16), uint4 stores
__global__ __launch_bounds__(128) void prep_bpt(const float* __restrict__ feat_b,
                                                const u16* __restrict__ WfT,
                                                u32* __restrict__ BpT32){
  int t = threadIdx.x, w = t >> 6, l = t & 63;
  int lr = l & 15, lk = l >> 4;
  int mrow = blockIdx.x*32 + w*16;               // 512 blocks x 2 waves
  f32x4 acc[16] = {};
  const float* ap = feat_b + (size_t)(mrow + lr)*128 + lk*8;
  #pragma unroll
  for (int ks = 0; ks < 4; ++ks){
    f4 a0 = *(const f4*)(ap + ks*32);
    f4 a1 = *(const f4*)(ap + ks*32 + 4);
    bf16x8 a = cvt8(a0, a1);
    #pragma unroll
    for (int cf = 0; cf < 16; ++cf){
      bf16x8 b = *(const bf16x8*)(WfT + (cf*16 + lr)*128 + ks*32 + lk*8);
      acc[cf] = __builtin_amdgcn_mfma_f32_16x16x32_bf16(a, b, acc[cf], 0, 0, 0);
    }
  }
  #pragma unroll
  for (int cf = 0; cf < 8; ++cf){
    int o = cf*16 + lr;
    uint4 v;
    v.x = (u32)f2bf(acc[cf][0]) | ((u32)f2bf(acc[cf+8][0]) << 16);
    v.y = (u32)f2bf(acc[cf][1]) | ((u32)f2bf(acc[cf+8][1]) << 16);
    v.z = (u32)f2bf(acc[cf][2]) | ((u32)f2bf(acc[cf+8][2]) << 16);
    v.w = (u32)f2bf(acc[cf][3]) | ((u32)f2bf(acc[cf+8][3]) << 16);
    *(uint4*)(BpT32 + (size_t)o*16384 + mrow + lk*4) = v;
  }
}

// CSR build
__global__ void hist_k(const int* __restrict__ dst, int* __restrict__ hist){
  int e = blockIdx.x*256 + threadIdx.x;
  atomicAdd(hist + dst[e], 1);
}

__global__ void scan_k(const int* __restrict__ hist, int* __restrict__ off,
                       int* __restrict__ cursor){
  __shared__ int part[256];
  int t = threadIdx.x;
  int loc[32]; int s = 0;
  #pragma unroll
  for (int i = 0; i < 32; ++i){ loc[i] = hist[t*32 + i]; s += loc[i]; }
  part[t] = s;
  __syncthreads();
  for (int d = 1; d < 256; d <<= 1){
    int v = (t >= d) ? part[t-d] : 0;
    __syncthreads();
    part[t] += v;
    __syncthreads();
  }
  int run = (t > 0) ? part[t-1] : 0;
  #pragma unroll
  for (int i = 0; i < 32; ++i){ off[t*32+i] = run; cursor[t*32+i] = run; run += loc[i]; }
  if (t == 255) off[NN] = run;
}

__global__ void fill_k(const int* __restrict__ src, const int* __restrict__ dst,
                       int* __restrict__ cursor, int* __restrict__ eidx){
  int e = blockIdx.x*256 + threadIdx.x;
  int pos = atomicAdd(cursor + dst[e], 1);
  eidx[pos] = src[e];
}

// agg: zout[n] = sum_{e: dst[e]=n} zin[src[e]]
__global__ __launch_bounds__(256) void agg_k(const float* __restrict__ zin,
                                             float* __restrict__ zout,
                                             const int* __restrict__ off,
                                             const int* __restrict__ eidx){
  int t = threadIdx.x;
  int node = blockIdx.x*8 + (t >> 5);
  int c = (t & 31)*4;
  int s = off[node], e = off[node+1];
  float a0=0.f, a1=0.f, a2=0.f, a3=0.f;
  for (int j = s; j < e; ++j){
    f4 v = *(const f4*)(zin + (size_t)eidx[j]*128 + c);
    a0 += v.x; a1 += v.y; a2 += v.z; a3 += v.w;
  }
  f4 r; r.x=a0; r.y=a1; r.z=a2; r.w=a3;
  *(f4*)(zout + (size_t)node*128 + c) = r;
}

// out = [feat_a, deg*feat_a, z0, z1, z2] @ Wcat + biases   (f32)
__global__ __launch_bounds__(256) void proj_all(
    const float* __restrict__ feat_a, const float* __restrict__ deg,
    const float* __restrict__ z0, const float* __restrict__ z1, const float* __restrict__ z2,
    const float* __restrict__ W_prev, const float* __restrict__ W_deg, const float* __restrict__ W_r,
    const float* __restrict__ b_prev, const float* __restrict__ b_deg,
    const float* __restrict__ b_r, const float* __restrict__ b_fuse,
    float* __restrict__ out)
{
  __shared__ float Xs[32][64];
  __shared__ float Ws[64][128];
  int t = threadIdx.x;
  int rbase = blockIdx.x*32;
  int o0 = (t & 15)*8, r0 = (t >> 4)*2;
  float acc[2][8] = {};
  for (int p = 0; p < 10; ++p){
    int seg = p >> 1, half = p & 1;
    {
      int row = t >> 3, e8 = t & 7;
      const float* bp = (seg <= 1) ? feat_a : (seg == 2) ? z0 : (seg == 3) ? z1 : z2;
      const float* sp = bp + (size_t)(rbase+row)*128 + half*64 + e8*8;
      f4 v0 = *(const f4*)sp;
      f4 v1 = *(const f4*)(sp+4);
      if (seg == 1){
        float d = deg[rbase+row];
        v0 *= d; v1 *= d;
      }
      *(f4*)&Xs[row][e8*8]   = v0;
      *(f4*)&Xs[row][e8*8+4] = v1;
    }
    #pragma unroll
    for (int it = 0; it < 8; ++it){
      int lin = it*1024 + t*4;
      int wr = lin >> 7, wc = lin & 127;
      int ksrc = p*64 + wr;
      int sg = ksrc >> 7, kin = ksrc & 127;
      const float* wp = (sg == 0) ? W_prev : (sg == 1) ? W_deg : (W_r + (size_t)(sg-2)*16384);
      *(f4*)&Ws[wr][wc] = *(const f4*)(wp + kin*128 + wc);
    }
    __syncthreads();
    #pragma unroll 8
    for (int kk = 0; kk < 64; ++kk){
      float x0 = Xs[r0][kk], x1 = Xs[r0+1][kk];
      f4 wa = *(const f4*)&Ws[kk][o0];
      f4 wb = *(const f4*)&Ws[kk][o0+4];
      acc[0][0]=fmaf(x0,wa.x,acc[0][0]); acc[0][1]=fmaf(x0,wa.y,acc[0][1]);
      acc[0][2]=fmaf(x0,wa.z,acc[0][2]); acc[0][3]=fmaf(x0,wa.w,acc[0][3]);
      acc[0][4]=fmaf(x0,wb.x,acc[0][4]); acc[0][5]=fmaf(x0,wb.y,acc[0][5]);
      acc[0][6]=fmaf(x0,wb.z,acc[0][6]); acc[0][7]=fmaf(x0,wb.w,acc[0][7]);
      acc[1][0]=fmaf(x1,wa.x,acc[1][0]); acc[1][1]=fmaf(x1,wa.y,acc[1][1]);
      acc[1][2]=fmaf(x1,wa.z,acc[1][2]); acc[1][3]=fmaf(x1,wa.w,acc[1][3]);
      acc[1][4]=fmaf(x1,wb.x,acc[1][4]); acc[1][5]=fmaf(x1,wb.y,acc[1][5]);
      acc[1][6]=fmaf(x1,wb.z,acc[1][6]); acc[1][7]=fmaf(x1,wb.w,acc[1][7]);
    }
    __syncthreads();
  }
  #pragma unroll
  for (int i = 0; i < 2; ++i){
    int r = rbase + r0 + i;
    #pragma unroll
    for (int j = 0; j < 8; ++j){
      int o = o0 + j;
      float bias = b_prev[o] + b_deg[o] + b_fuse[o] + b_r[o] + b_r[128+o] + b_r[256+o];
      out[(size_t)r*128 + o] = acc[i][j] + bias;
    }
  }
}

// C += pm_pd_flat(8192x32768 f32->bf16) @ Bp(32768x128 bf16)
// R7 structure with counted-waitcnt barriers: the per-tile barriers no longer
// drain vmcnt(0), so the A-prefetch stream stays in flight across tiles.
// FIFO discipline: B-gloads issued BEFORE A-gloads so ds_write's counted
// vmcnt wait does not transitively retire the A stream.
__global__ __launch_bounds__(256, 2) void fuse_gemm(const float* __restrict__ A,
                                                    const u16* __restrict__ BpT,
                                                    float* __restrict__ out){
  __shared__ u16 Bs[128*64];
  int b = blockIdx.x;
  int rowtile = b & 63, kc = b >> 6;
  int t = threadIdx.x, w = t >> 6, l = t & 63;
  int lr = l & 15, lk = l >> 4;
  size_t kbase = (size_t)kc*4096;
  int row0 = rowtile*128 + w*32 + lr;
  const float* a0p = A + (size_t)row0*K2 + kbase + lk*8;
  const float* a1p = a0p + (size_t)16*K2;
  int so[4], soct;
  soct = t & 7;
  #pragma unroll
  for (int pp = 0; pp < 4; ++pp) so[pp] = (pp*256 + t) >> 3;
  f32x4 acc[2][8] = {};
  f4 Ar[2][8];
  // prologue: prefetch tile-0 A
  {
    const f4* p0 = (const f4*)a0p;
    const f4* p1 = (const f4*)a1p;
    Ar[0][0] = __builtin_nontemporal_load(p0);
    Ar[0][1] = __builtin_nontemporal_load(p0 + 1);
    Ar[0][2] = __builtin_nontemporal_load(p1);
    Ar[0][3] = __builtin_nontemporal_load(p1 + 1);
    Ar[0][4] = __builtin_nontemporal_load(p0 + 8);
    Ar[0][5] = __builtin_nontemporal_load(p0 + 9);
    Ar[0][6] = __builtin_nontemporal_load(p1 + 8);
    Ar[0][7] = __builtin_nontemporal_load(p1 + 9);
  }
  #pragma unroll 2
  for (int tile = 0; tile < 64; ++tile){
    int cur = tile & 1;                          // static after unroll-2
    // (1) B(t) global loads FIRST (FIFO head)
    uint4 bv[4];
    size_t kt = kbase + tile*64;
    #pragma unroll
    for (int pp = 0; pp < 4; ++pp)
      bv[pp] = *(const uint4*)(BpT + (size_t)so[pp]*K2 + kt + soct*8);
    // (2) A(t+1) prefetch second — stays in flight across both barriers
    if (tile < 63){
      const f4* p0 = (const f4*)(a0p + (tile+1)*64);
      const f4* p1 = (const f4*)(a1p + (tile+1)*64);
      Ar[cur^1][0] = __builtin_nontemporal_load(p0);
      Ar[cur^1][1] = __builtin_nontemporal_load(p0 + 1);
      Ar[cur^1][2] = __builtin_nontemporal_load(p1);
      Ar[cur^1][3] = __builtin_nontemporal_load(p1 + 1);
      Ar[cur^1][4] = __builtin_nontemporal_load(p0 + 8);
      Ar[cur^1][5] = __builtin_nontemporal_load(p0 + 9);
      Ar[cur^1][6] = __builtin_nontemporal_load(p1 + 8);
      Ar[cur^1][7] = __builtin_nontemporal_load(p1 + 9);
    }
    // (3) ds_write B(t) (compiler inserts counted vmcnt for bv only)
    #pragma unroll
    for (int pp = 0; pp < 4; ++pp)
      *(uint4*)((char*)Bs + so[pp]*128 + ((soct ^ (so[pp] & 7)) << 4)) = bv[pp];
    // barrier 1: ds_writes visible; NO vmcnt drain
    asm volatile("s_waitcnt lgkmcnt(0)" ::: "memory");
    __builtin_amdgcn_sched_barrier(0);
    __builtin_amdgcn_s_barrier();
    __builtin_amdgcn_sched_barrier(0);
    // (4) compute tile t
    #pragma unroll
    for (int s = 0; s < 2; ++s){
      bf16x8 a0 = cvt8t(Ar[cur][s*4+0], Ar[cur][s*4+1]);
      bf16x8 a1 = cvt8t(Ar[cur][s*4+2], Ar[cur][s*4+3]);
      int khalf = s*4 + lk;
      #pragma unroll
      for (int cf = 0; cf < 8; ++cf){
        int o = cf*16 + lr;
        bf16x8 bfr = *(const bf16x8*)((char*)Bs + o*128 + ((khalf ^ (o & 7)) << 4));
        acc[0][cf] = __builtin_amdgcn_mfma_f32_16x16x32_bf16(a0, bfr, acc[0][cf], 0, 0, 0);
        acc[1][cf] = __builtin_amdgcn_mfma_f32_16x16x32_bf16(a1, bfr, acc[1][cf], 0, 0, 0);
      }
    }
    // barrier 2: LDS WAR protection only (all ds_reads already consumed)
    __builtin_amdgcn_sched_barrier(0);
    __builtin_amdgcn_s_barrier();
    __builtin_amdgcn_sched_barrier(0);
  }
  int orow = rowtile*128 + w*32 + lk*4;
  #pragma unroll
  for (int rf = 0; rf < 2; ++rf){
    #pragma unroll
    for (int cf = 0; cf < 8; ++cf){
      #pragma unroll
      for (int j = 0; j < 4; ++j){
        unsafeAtomicAdd(out + (size_t)(orow + rf*16 + j)*128 + cf*16 + lr, acc[rf][cf][j]);
      }
    }
  }
}

// BatchNorm stats with half-ReLU on read; row-contiguous reads
__global__ __launch_bounds__(256) void colstats(const float* __restrict__ acc,
                                                float* __restrict__ gsum,
                                                float* __restrict__ gsumsq){
  __shared__ float s1[8][128], s2[8][128];
  int t = threadIdx.x;
  int c4 = (t & 31)*4, rsub = t >> 5;
  int rbase = blockIdx.x*32;
  f4 sum = {0,0,0,0}, sq = {0,0,0,0};
  #pragma unroll
  for (int i = 0; i < 4; ++i){
    f4 v = *(const f4*)(acc + (size_t)(rbase + rsub + i*8)*128 + c4);
    if (c4 >= 64){
      v.x=fmaxf(v.x,0.f); v.y=fmaxf(v.y,0.f); v.z=fmaxf(v.z,0.f); v.w=fmaxf(v.w,0.f);
    }
    sum += v; sq += v*v;
  }
  *(f4*)&s1[rsub][c4] = sum;
  *(f4*)&s2[rsub][c4] = sq;
  __syncthreads();
  if (t < 128){
    float a = 0.f, b2 = 0.f;
    #pragma unroll
    for (int r = 0; r < 8; ++r){ a += s1[r][t]; b2 += s2[r][t]; }
    unsafeAtomicAdd(gsum + t, a);
    unsafeAtomicAdd(gsumsq + t, b2);
  }
}

// merged bn_final + bn_apply: each thread derives its 4 cols' scale/shift from gsum
__global__ __launch_bounds__(256) void bn_apply(float* __restrict__ out,
                                                const float* __restrict__ gsum,
                                                const float* __restrict__ gsumsq,
                                                const float* __restrict__ gamma,
                                                const float* __restrict__ beta){
  int i = blockIdx.x*256 + threadIdx.x;
  int j = i & 31;
  f4 sc, sh;
  #pragma unroll
  for (int k = 0; k < 4; ++k){
    int c = j*4 + k;
    float mean = gsum[c] * (1.f/8192.f);
    float var  = gsumsq[c] * (1.f/8192.f) - mean*mean;
    float s = rsqrtf(var + 1e-5f) * gamma[c];
    ((float*)&sc)[k] = s;
    ((float*)&sh)[k] = beta[c] - mean*s;
  }
  f4* o4 = (f4*)out;
  f4 v = o4[i];
  if (j >= 16){
    v.x=fmaxf(v.x,0.f); v.y=fmaxf(v.y,0.f); v.z=fmaxf(v.z,0.f); v.w=fmaxf(v.w,0.f);
  }
  v.x = fmaf(v.x,sc.x,sh.x); v.y = fmaf(v.y,sc.y,sh.y);
  v.z = fmaf(v.z,sc.z,sh.z); v.w = fmaf(v.w,sc.w,sh.w);
  o4[i] = v;
}

extern "C" void kernel_launch(void* const* d_in, const int* in_sizes, int n_in,
                              void* d_out, int out_size, void* d_ws, size_t ws_size,
                              hipStream_t stream) {
  const float* feat_a = (const float*)d_in[0];
  const float* feat_b = (const float*)d_in[1];
  const float* deg    = (const float*)d_in[2];
  const float* pm_pd  = (const float*)d_in[3];
  const int*   src    = (const int*)d_in[4];
  const int*   dst    = (const int*)d_in[5];
  const float* W_prev = (const float*)d_in[6];
  const float* b_prev = (const float*)d_in[7];
  const float* W_deg  = (const float*)d_in[8];
  const float* b_deg  = (const float*)d_in[9];
  const float* W_r    = (const float*)d_in[10];
  const float* b_r    = (const float*)d_in[11];
  const float* W_fuse = (const float*)d_in[12];
  const float* b_fuse = (const float*)d_in[13];
  const float* gamma  = (const float*)d_in[14];
  const float* beta   = (const float*)d_in[15];
  float* out = (float*)d_out;

  char* w = (char*)d_ws;
  u16*   BpT    = (u16*)  (w + 0);          // 8 MB interleaved B'
  float* z0     = (float*)(w + 8388608);
  float* z1     = (float*)(w + 12582912);
  float* ztmp   = (float*)(w + 16777216);
  float* z2     = (float*)(w + 20971520);
  u16*   WfT    = (u16*)  (w + 25165824);
  int*   hist   = (int*)  (w + 25231360);
  int*   off    = (int*)  (w + 25264128);
  int*   cursor = (int*)  (w + 25296912);
  int*   eidx   = (int*)  (w + 25329680);
  float* gsum   = (float*)(w + 25853968);
  float* gsumsq = gsum + 128;
  if (ws_size < (size_t)25856016) return;

  hipMemsetAsync(hist, 0, NN*sizeof(int), stream);
  hipMemsetAsync(gsum, 0, 256*sizeof(float), stream);

  wft_k<<<256, 128, 0, stream>>>(W_fuse, WfT);
  prep_bpt<<<MM/32, 128, 0, stream>>>(feat_b, WfT, (u32*)BpT);

  hist_k<<<EE/256, 256, 0, stream>>>(dst, hist);
  scan_k<<<1, 256, 0, stream>>>(hist, off, cursor);
  fill_k<<<EE/256, 256, 0, stream>>>(src, dst, cursor, eidx);

  agg_k<<<NN/8, 256, 0, stream>>>(feat_a, z0, off, eidx);
  agg_k<<<NN/8, 256, 0, stream>>>(z0, z1, off, eidx);
  agg_k<<<NN/8, 256, 0, stream>>>(z1, ztmp, off, eidx);
  agg_k<<<NN/8, 256, 0, stream>>>(ztmp, z2, off, eidx);

  proj_all<<<NN/32, 256, 0, stream>>>(feat_a, deg, z0, z1, z2,
                                      W_prev, W_deg, W_r, b_prev, b_deg, b_r, b_fuse, out);

  fuse_gemm<<<512, 256, 0, stream>>>(pm_pd, BpT, out);

  colstats<<<NN/32, 256, 0, stream>>>(out, gsum, gsumsq);
  bn_apply<<<NN*128/4/256, 256, 0, stream>>>(out, gsum, gsumsq, gamma, beta);
}

// Round 13
// 425.616 us; speedup vs baseline: 1.5296x; 1.0284x over previous
//
#include <hip/hip_runtime.h>
#include <hip/hip_bf16.h>

#define NN 8192
#define MM 16384
#define EE 131072
#define K2 32768

typedef unsigned short u16;
typedef unsigned int u32;
typedef __attribute__((ext_vector_type(8))) short bf16x8;
typedef __attribute__((ext_vector_type(4))) float f32x4;
typedef __attribute__((ext_vector_type(4))) float f4;

__device__ __forceinline__ u16 f2bf(float f){
  union { float f; unsigned u; } x; x.f = f;
  return (u16)((x.u + 0x7FFFu + ((x.u >> 16) & 1u)) >> 16);   // RNE
}

__device__ __forceinline__ bf16x8 cvt8(f4 a, f4 b){            // RNE path (prep kernels)
  bf16x8 r;
  r[0]=(short)f2bf(a.x); r[1]=(short)f2bf(a.y);
  r[2]=(short)f2bf(a.z); r[3]=(short)f2bf(a.w);
  r[4]=(short)f2bf(b.x); r[5]=(short)f2bf(b.y);
  r[6]=(short)f2bf(b.z); r[7]=(short)f2bf(b.w);
  return r;
}

// truncating pack: one v_perm_b32 per 2 floats (hot path: fuse_gemm A-convert)
__device__ __forceinline__ bf16x8 cvt8t(f4 a, f4 b){
  union { u32 u[4]; bf16x8 v; } r;
  r.u[0] = __builtin_amdgcn_perm(__float_as_uint(a.y), __float_as_uint(a.x), 0x07060302u);
  r.u[1] = __builtin_amdgcn_perm(__float_as_uint(a.w), __float_as_uint(a.z), 0x07060302u);
  r.u[2] = __builtin_amdgcn_perm(__float_as_uint(b.y), __float_as_uint(b.x), 0x07060302u);
  r.u[3] = __builtin_amdgcn_perm(__float_as_uint(b.w), __float_as_uint(b.z), 0x07060302u);
  return r.v;
}

// WfT[co][j] = bf16(W_fuse[(co>>7)*128 + j][co&127])
__global__ void wft_k(const float* __restrict__ W_fuse, u16* __restrict__ WfT){
  int co = blockIdx.x, j = threadIdx.x;
  int c = co >> 7, o = co & 127;
  WfT[co*128 + j] = f2bf(W_fuse[(c*128 + j)*128 + o]);
}

// BpT[o][2m+c] = bf16(sum_j feat_b[m][j] * W_fuse[c*128+j][o]); packed u32 (c0|c1<<16), uint4 stores
__global__ __launch_bounds__(128) void prep_bpt(const float* __restrict__ feat_b,
                                                const u16* __restrict__ WfT,
                                                u32* __restrict__ BpT32){
  int t = threadIdx.x, w = t >> 6, l = t & 63;
  int lr = l & 15, lk = l >> 4;
  int mrow = blockIdx.x*32 + w*16;               // 512 blocks x 2 waves
  f32x4 acc[16] = {};
  const float* ap = feat_b + (size_t)(mrow + lr)*128 + lk*8;
  #pragma unroll
  for (int ks = 0; ks < 4; ++ks){
    f4 a0 = *(const f4*)(ap + ks*32);
    f4 a1 = *(const f4*)(ap + ks*32 + 4);
    bf16x8 a = cvt8(a0, a1);
    #pragma unroll
    for (int cf = 0; cf < 16; ++cf){
      bf16x8 b = *(const bf16x8*)(WfT + (cf*16 + lr)*128 + ks*32 + lk*8);
      acc[cf] = __builtin_amdgcn_mfma_f32_16x16x32_bf16(a, b, acc[cf], 0, 0, 0);
    }
  }
  #pragma unroll
  for (int cf = 0; cf < 8; ++cf){
    int o = cf*16 + lr;
    uint4 v;
    v.x = (u32)f2bf(acc[cf][0]) | ((u32)f2bf(acc[cf+8][0]) << 16);
    v.y = (u32)f2bf(acc[cf][1]) | ((u32)f2bf(acc[cf+8][1]) << 16);
    v.z = (u32)f2bf(acc[cf][2]) | ((u32)f2bf(acc[cf+8][2]) << 16);
    v.w = (u32)f2bf(acc[cf][3]) | ((u32)f2bf(acc[cf+8][3]) << 16);
    *(uint4*)(BpT32 + (size_t)o*16384 + mrow + lk*4) = v;
  }
}

// CSR build
__global__ void hist_k(const int* __restrict__ dst, int* __restrict__ hist){
  int e = blockIdx.x*256 + threadIdx.x;
  atomicAdd(hist + dst[e], 1);
}

__global__ void scan_k(const int* __restrict__ hist, int* __restrict__ off,
                       int* __restrict__ cursor){
  __shared__ int part[256];
  int t = threadIdx.x;
  int loc[32]; int s = 0;
  #pragma unroll
  for (int i = 0; i < 32; ++i){ loc[i] = hist[t*32 + i]; s += loc[i]; }
  part[t] = s;
  __syncthreads();
  for (int d = 1; d < 256; d <<= 1){
    int v = (t >= d) ? part[t-d] : 0;
    __syncthreads();
    part[t] += v;
    __syncthreads();
  }
  int run = (t > 0) ? part[t-1] : 0;
  #pragma unroll
  for (int i = 0; i < 32; ++i){ off[t*32+i] = run; cursor[t*32+i] = run; run += loc[i]; }
  if (t == 255) off[NN] = run;
}

__global__ void fill_k(const int* __restrict__ src, const int* __restrict__ dst,
                       int* __restrict__ cursor, int* __restrict__ eidx){
  int e = blockIdx.x*256 + threadIdx.x;
  int pos = atomicAdd(cursor + dst[e], 1);
  eidx[pos] = src[e];
}

// agg: zout[n] = sum_{e: dst[e]=n} zin[src[e]]
__global__ __launch_bounds__(256) void agg_k(const float* __restrict__ zin,
                                             float* __restrict__ zout,
                                             const int* __restrict__ off,
                                             const int* __restrict__ eidx){
  int t = threadIdx.x;
  int node = blockIdx.x*8 + (t >> 5);
  int c = (t & 31)*4;
  int s = off[node], e = off[node+1];
  float a0=0.f, a1=0.f, a2=0.f, a3=0.f;
  for (int j = s; j < e; ++j){
    f4 v = *(const f4*)(zin + (size_t)eidx[j]*128 + c);
    a0 += v.x; a1 += v.y; a2 += v.z; a3 += v.w;
  }
  f4 r; r.x=a0; r.y=a1; r.z=a2; r.w=a3;
  *(f4*)(zout + (size_t)node*128 + c) = r;
}

// out = [feat_a, deg*feat_a, z0, z1, z2] @ Wcat + biases   (f32)
__global__ __launch_bounds__(256) void proj_all(
    const float* __restrict__ feat_a, const float* __restrict__ deg,
    const float* __restrict__ z0, const float* __restrict__ z1, const float* __restrict__ z2,
    const float* __restrict__ W_prev, const float* __restrict__ W_deg, const float* __restrict__ W_r,
    const float* __restrict__ b_prev, const float* __restrict__ b_deg,
    const float* __restrict__ b_r, const float* __restrict__ b_fuse,
    float* __restrict__ out)
{
  __shared__ float Xs[32][64];
  __shared__ float Ws[64][128];
  int t = threadIdx.x;
  int rbase = blockIdx.x*32;
  int o0 = (t & 15)*8, r0 = (t >> 4)*2;
  float acc[2][8] = {};
  for (int p = 0; p < 10; ++p){
    int seg = p >> 1, half = p & 1;
    {
      int row = t >> 3, e8 = t & 7;
      const float* bp = (seg <= 1) ? feat_a : (seg == 2) ? z0 : (seg == 3) ? z1 : z2;
      const float* sp = bp + (size_t)(rbase+row)*128 + half*64 + e8*8;
      f4 v0 = *(const f4*)sp;
      f4 v1 = *(const f4*)(sp+4);
      if (seg == 1){
        float d = deg[rbase+row];
        v0 *= d; v1 *= d;
      }
      *(f4*)&Xs[row][e8*8]   = v0;
      *(f4*)&Xs[row][e8*8+4] = v1;
    }
    #pragma unroll
    for (int it = 0; it < 8; ++it){
      int lin = it*1024 + t*4;
      int wr = lin >> 7, wc = lin & 127;
      int ksrc = p*64 + wr;
      int sg = ksrc >> 7, kin = ksrc & 127;
      const float* wp = (sg == 0) ? W_prev : (sg == 1) ? W_deg : (W_r + (size_t)(sg-2)*16384);
      *(f4*)&Ws[wr][wc] = *(const f4*)(wp + kin*128 + wc);
    }
    __syncthreads();
    #pragma unroll 8
    for (int kk = 0; kk < 64; ++kk){
      float x0 = Xs[r0][kk], x1 = Xs[r0+1][kk];
      f4 wa = *(const f4*)&Ws[kk][o0];
      f4 wb = *(const f4*)&Ws[kk][o0+4];
      acc[0][0]=fmaf(x0,wa.x,acc[0][0]); acc[0][1]=fmaf(x0,wa.y,acc[0][1]);
      acc[0][2]=fmaf(x0,wa.z,acc[0][2]); acc[0][3]=fmaf(x0,wa.w,acc[0][3]);
      acc[0][4]=fmaf(x0,wb.x,acc[0][4]); acc[0][5]=fmaf(x0,wb.y,acc[0][5]);
      acc[0][6]=fmaf(x0,wb.z,acc[0][6]); acc[0][7]=fmaf(x0,wb.w,acc[0][7]);
      acc[1][0]=fmaf(x1,wa.x,acc[1][0]); acc[1][1]=fmaf(x1,wa.y,acc[1][1]);
      acc[1][2]=fmaf(x1,wa.z,acc[1][2]); acc[1][3]=fmaf(x1,wa.w,acc[1][3]);
      acc[1][4]=fmaf(x1,wb.x,acc[1][4]); acc[1][5]=fmaf(x1,wb.y,acc[1][5]);
      acc[1][6]=fmaf(x1,wb.z,acc[1][6]); acc[1][7]=fmaf(x1,wb.w,acc[1][7]);
    }
    __syncthreads();
  }
  #pragma unroll
  for (int i = 0; i < 2; ++i){
    int r = rbase + r0 + i;
    #pragma unroll
    for (int j = 0; j < 8; ++j){
      int o = o0 + j;
      float bias = b_prev[o] + b_deg[o] + b_fuse[o] + b_r[o] + b_r[128+o] + b_r[256+o];
      out[(size_t)r*128 + o] = acc[i][j] + bias;
    }
  }
}

// C += pm_pd_flat(8192x32768 f32->bf16) @ Bp(32768x128 bf16)
// R7 verbatim: BM=128, BK=64, KSPLIT=8, grid 512, 2 blocks/CU, LDS B-tile,
// A-register ping-pong prefetch issued before the staging barrier.
__global__ __launch_bounds__(256, 2) void fuse_gemm(const float* __restrict__ A,
                                                    const u16* __restrict__ BpT,
                                                    float* __restrict__ out){
  __shared__ u16 Bs[128*64];
  int b = blockIdx.x;
  int rowtile = b & 63, kc = b >> 6;
  int t = threadIdx.x, w = t >> 6, l = t & 63;
  int lr = l & 15, lk = l >> 4;
  size_t kbase = (size_t)kc*4096;
  int row0 = rowtile*128 + w*32 + lr;
  const float* a0p = A + (size_t)row0*K2 + kbase + lk*8;
  const float* a1p = a0p + (size_t)16*K2;
  f32x4 acc[2][8] = {};
  f4 Ar[2][8];
  // prologue: prefetch tile 0
  {
    const f4* p0 = (const f4*)a0p;
    const f4* p1 = (const f4*)a1p;
    Ar[0][0] = __builtin_nontemporal_load(p0);
    Ar[0][1] = __builtin_nontemporal_load(p0 + 1);
    Ar[0][2] = __builtin_nontemporal_load(p1);
    Ar[0][3] = __builtin_nontemporal_load(p1 + 1);
    Ar[0][4] = __builtin_nontemporal_load(p0 + 8);   // +32 floats
    Ar[0][5] = __builtin_nontemporal_load(p0 + 9);
    Ar[0][6] = __builtin_nontemporal_load(p1 + 8);
    Ar[0][7] = __builtin_nontemporal_load(p1 + 9);
  }
  #pragma unroll 2
  for (int tile = 0; tile < 64; ++tile){
    int cur = tile & 1;                          // static after unroll-2
    // issue next tile's A-loads first (long-latency HBM stream)
    if (tile < 63){
      const f4* p0 = (const f4*)(a0p + (tile+1)*64);
      const f4* p1 = (const f4*)(a1p + (tile+1)*64);
      Ar[cur^1][0] = __builtin_nontemporal_load(p0);
      Ar[cur^1][1] = __builtin_nontemporal_load(p0 + 1);
      Ar[cur^1][2] = __builtin_nontemporal_load(p1);
      Ar[cur^1][3] = __builtin_nontemporal_load(p1 + 1);
      Ar[cur^1][4] = __builtin_nontemporal_load(p0 + 8);
      Ar[cur^1][5] = __builtin_nontemporal_load(p0 + 9);
      Ar[cur^1][6] = __builtin_nontemporal_load(p1 + 8);
      Ar[cur^1][7] = __builtin_nontemporal_load(p1 + 9);
    }
    // stage B tile (128 o x 64 k), 16B-slot XOR swizzle
    size_t kt = kbase + tile*64;
    #pragma unroll
    for (int pp = 0; pp < 4; ++pp){
      int q = pp*256 + t;
      int o = q >> 3, oct = q & 7;
      uint4 v = *(const uint4*)(BpT + (size_t)o*K2 + kt + oct*8);
      *(uint4*)((char*)Bs + o*128 + ((oct ^ (o & 7)) << 4)) = v;
    }
    __syncthreads();                             // drains staging + prefetch together
    #pragma unroll
    for (int s = 0; s < 2; ++s){
      bf16x8 a0 = cvt8t(Ar[cur][s*4+0], Ar[cur][s*4+1]);
      bf16x8 a1 = cvt8t(Ar[cur][s*4+2], Ar[cur][s*4+3]);
      int khalf = s*4 + lk;
      #pragma unroll
      for (int cf = 0; cf < 8; ++cf){
        int o = cf*16 + lr;
        bf16x8 bfr = *(const bf16x8*)((char*)Bs + o*128 + ((khalf ^ (o & 7)) << 4));
        acc[0][cf] = __builtin_amdgcn_mfma_f32_16x16x32_bf16(a0, bfr, acc[0][cf], 0, 0, 0);
        acc[1][cf] = __builtin_amdgcn_mfma_f32_16x16x32_bf16(a1, bfr, acc[1][cf], 0, 0, 0);
      }
    }
    __syncthreads();
  }
  int orow = rowtile*128 + w*32 + lk*4;
  #pragma unroll
  for (int rf = 0; rf < 2; ++rf){
    #pragma unroll
    for (int cf = 0; cf < 8; ++cf){
      #pragma unroll
      for (int j = 0; j < 4; ++j){
        unsafeAtomicAdd(out + (size_t)(orow + rf*16 + j)*128 + cf*16 + lr, acc[rf][cf][j]);
      }
    }
  }
}

// BatchNorm stats with half-ReLU on read; row-contiguous reads
__global__ __launch_bounds__(256) void colstats(const float* __restrict__ acc,
                                                float* __restrict__ gsum,
                                                float* __restrict__ gsumsq){
  __shared__ float s1[8][128], s2[8][128];
  int t = threadIdx.x;
  int c4 = (t & 31)*4, rsub = t >> 5;
  int rbase = blockIdx.x*32;
  f4 sum = {0,0,0,0}, sq = {0,0,0,0};
  #pragma unroll
  for (int i = 0; i < 4; ++i){
    f4 v = *(const f4*)(acc + (size_t)(rbase + rsub + i*8)*128 + c4);
    if (c4 >= 64){
      v.x=fmaxf(v.x,0.f); v.y=fmaxf(v.y,0.f); v.z=fmaxf(v.z,0.f); v.w=fmaxf(v.w,0.f);
    }
    sum += v; sq += v*v;
  }
  *(f4*)&s1[rsub][c4] = sum;
  *(f4*)&s2[rsub][c4] = sq;
  __syncthreads();
  if (t < 128){
    float a = 0.f, b2 = 0.f;
    #pragma unroll
    for (int r = 0; r < 8; ++r){ a += s1[r][t]; b2 += s2[r][t]; }
    unsafeAtomicAdd(gsum + t, a);
    unsafeAtomicAdd(gsumsq + t, b2);
  }
}

// merged bn_final + bn_apply: each thread derives its 4 cols' scale/shift from gsum
__global__ __launch_bounds__(256) void bn_apply(float* __restrict__ out,
                                                const float* __restrict__ gsum,
                                                const float* __restrict__ gsumsq,
                                                const float* __restrict__ gamma,
                                                const float* __restrict__ beta){
  int i = blockIdx.x*256 + threadIdx.x;
  int j = i & 31;
  f4 sc, sh;
  #pragma unroll
  for (int k = 0; k < 4; ++k){
    int c = j*4 + k;
    float mean = gsum[c] * (1.f/8192.f);
    float var  = gsumsq[c] * (1.f/8192.f) - mean*mean;
    float s = rsqrtf(var + 1e-5f) * gamma[c];
    ((float*)&sc)[k] = s;
    ((float*)&sh)[k] = beta[c] - mean*s;
  }
  f4* o4 = (f4*)out;
  f4 v = o4[i];
  if (j >= 16){
    v.x=fmaxf(v.x,0.f); v.y=fmaxf(v.y,0.f); v.z=fmaxf(v.z,0.f); v.w=fmaxf(v.w,0.f);
  }
  v.x = fmaf(v.x,sc.x,sh.x); v.y = fmaf(v.y,sc.y,sh.y);
  v.z = fmaf(v.z,sc.z,sh.z); v.w = fmaf(v.w,sc.w,sh.w);
  o4[i] = v;
}

extern "C" void kernel_launch(void* const* d_in, const int* in_sizes, int n_in,
                              void* d_out, int out_size, void* d_ws, size_t ws_size,
                              hipStream_t stream) {
  const float* feat_a = (const float*)d_in[0];
  const float* feat_b = (const float*)d_in[1];
  const float* deg    = (const float*)d_in[2];
  const float* pm_pd  = (const float*)d_in[3];
  const int*   src    = (const int*)d_in[4];
  const int*   dst    = (const int*)d_in[5];
  const float* W_prev = (const float*)d_in[6];
  const float* b_prev = (const float*)d_in[7];
  const float* W_deg  = (const float*)d_in[8];
  const float* b_deg  = (const float*)d_in[9];
  const float* W_r    = (const float*)d_in[10];
  const float* b_r    = (const float*)d_in[11];
  const float* W_fuse = (const float*)d_in[12];
  const float* b_fuse = (const float*)d_in[13];
  const float* gamma  = (const float*)d_in[14];
  const float* beta   = (const float*)d_in[15];
  float* out = (float*)d_out;

  char* w = (char*)d_ws;
  u16*   BpT    = (u16*)  (w + 0);          // 8 MB interleaved B'
  float* z0     = (float*)(w + 8388608);
  float* z1     = (float*)(w + 12582912);
  float* ztmp   = (float*)(w + 16777216);
  float* z2     = (float*)(w + 20971520);
  u16*   WfT    = (u16*)  (w + 25165824);
  int*   hist   = (int*)  (w + 25231360);
  int*   off    = (int*)  (w + 25264128);
  int*   cursor = (int*)  (w + 25296912);
  int*   eidx   = (int*)  (w + 25329680);
  float* gsum   = (float*)(w + 25853968);
  float* gsumsq = gsum + 128;
  if (ws_size < (size_t)25856016) return;

  hipMemsetAsync(hist, 0, NN*sizeof(int), stream);
  hipMemsetAsync(gsum, 0, 256*sizeof(float), stream);

  wft_k<<<256, 128, 0, stream>>>(W_fuse, WfT);
  prep_bpt<<<MM/32, 128, 0, stream>>>(feat_b, WfT, (u32*)BpT);

  hist_k<<<EE/256, 256, 0, stream>>>(dst, hist);
  scan_k<<<1, 256, 0, stream>>>(hist, off, cursor);
  fill_k<<<EE/256, 256, 0, stream>>>(src, dst, cursor, eidx);

  agg_k<<<NN/8, 256, 0, stream>>>(feat_a, z0, off, eidx);
  agg_k<<<NN/8, 256, 0, stream>>>(z0, z1, off, eidx);
  agg_k<<<NN/8, 256, 0, stream>>>(z1, ztmp, off, eidx);
  agg_k<<<NN/8, 256, 0, stream>>>(ztmp, z2, off, eidx);

  proj_all<<<NN/32, 256, 0, stream>>>(feat_a, deg, z0, z1, z2,
                                      W_prev, W_deg, W_r, b_prev, b_deg, b_r, b_fuse, out);

  fuse_gemm<<<512, 256, 0, stream>>>(pm_pd, BpT, out);

  colstats<<<NN/32, 256, 0, stream>>>(out, gsum, gsumsq);
  bn_apply<<<NN*128/4/256, 256, 0, stream>>>(out, gsum, gsumsq, gamma, beta);
}